// Round 15
// baseline (311.859 us; speedup 1.0000x reference)
//
#include <hip/hip_runtime.h>
#include <hip/hip_bf16.h>
#include <stdint.h>

typedef short    s16x8  __attribute__((ext_vector_type(8)));
typedef __bf16   bf16x8 __attribute__((ext_vector_type(8)));
typedef float    f32x4  __attribute__((ext_vector_type(4)));

__device__ __forceinline__ unsigned short f2bf(float f) {
    union { float f; unsigned u; } v; v.f = f;
    unsigned r = v.u + 0x7FFFu + ((v.u >> 16) & 1u);
    return (unsigned short)(r >> 16);
}
__device__ __forceinline__ float bf2f(unsigned short s) {
    union { unsigned u; float f; } v; v.u = ((unsigned)s) << 16;
    return v.f;
}

__device__ __forceinline__ void gload16(const void* g, void* l) {
    __builtin_amdgcn_global_load_lds(
        (const __attribute__((address_space(1))) void*)(uintptr_t)g,
        (__attribute__((address_space(3))) void*)(uintptr_t)l,
        16, 0, 0);
}

// ---------------- fp32 -> bf16 conversion (x and weights) -------------------
__global__ __launch_bounds__(256) void cvt_bf16(const float* __restrict__ in,
                                                unsigned short* __restrict__ out,
                                                int n4) {
    int i = blockIdx.x * blockDim.x + threadIdx.x;
    int stride = gridDim.x * blockDim.x;
    for (; i < n4; i += stride) {
        const float4 v = *(const float4*)(in + (size_t)i * 4);
        ushort4 o;
        o.x = f2bf(v.x); o.y = f2bf(v.y); o.z = f2bf(v.z); o.w = f2bf(v.w);
        *(ushort4*)(out + (size_t)i * 4) = o;
    }
}

// ---------------- 128x128 bf16 GEMM — TRUE counted-vmcnt pipeline -----------
// KEY FIX (round-15): R10/R11/R14 all used __syncthreads(), which compiles to
// s_waitcnt vmcnt(0) lgkmcnt(0) + s_barrier — draining every prefetch at
// every K-tile boundary. This kernel keeps the R10/R11 geometry (128^2 tile,
// 4 waves 2x2, 64x64/wave, BK=32, 2 blocks/CU) but uses a 4-slot LDS ring +
// RAW s_barrier + hand-counted vmcnt so 2 K-tiles (8 loads/thread) stay in
// flight ACROSS the barrier (T4, m218: counted-vs-drain = +38-73%).
// Safety: publish = per-wave vmcnt(8) precedes barrier (own slab-t loads
// landed; all waves => slab t visible). WAR = stage(t+3) writes slot
// (t-1)&3 whose reads completed before barrier-top-of-t; stage issued after.
// sched_barrier(0) pins ds_reads below the raw barrier (guide rule 18).
// T1 XCD swizzle, T2 source-XOR swizzle (0 conflicts measured), T5 setprio.
template<int K, bool OUT_BF16>
__global__ __launch_bounds__(256, 2) void gemm128r(
        const unsigned short* __restrict__ A,   // [M][K] bf16
        const unsigned short* __restrict__ B,   // [N][K] bf16
        const float* __restrict__ bias,         // [N] fp32
        void* __restrict__ Cvoid,               // [M][N] bf16 or fp32
        int M, int N, int ntn) {
    constexpr int BM = 128, BN = 128, BK = 32, NT = K / BK;   // NT = 16
    __shared__ __align__(16) unsigned short As[4][BM * BK];   // 4 x 8 KiB
    __shared__ __align__(16) unsigned short Bs[4][BN * BK];   // 4 x 8 KiB
    const int tid  = threadIdx.x;
    const int lane = tid & 63;
    const int wv   = tid >> 6;                  // 4 waves
    const int nwg  = (int)gridDim.x;
    const int wg   = ((int)blockIdx.x & 7) * (nwg >> 3) + ((int)blockIdx.x >> 3);
    const int bm   = wg / ntn;
    const int bn   = wg % ntn;
    const int wr   = (wv >> 1) * 64;    // wave M-offset in tile
    const int wc   = (wv & 1) * 64;     // wave N-offset in tile
    const int lr   = lane & 15;
    const int ls   = lane >> 4;         // k-slot 0..3

    const unsigned short* Ag = A + (size_t)bm * BM * K;
    const unsigned short* Bg = B + (size_t)bn * BN * K;

    // Stage K-slab t into ring slot t&3 (A,B 128x32 tiles, 2+2 gloads/thread).
    // Linear LDS dest; T2 swizzle on the global source slot (involution).
    auto stage = [&](int t) {
        char* la = (char*)As[t & 3];
        char* lb = (char*)Bs[t & 3];
        #pragma unroll
        for (int p = 0; p < 2; ++p) {
            const int c     = p * 256 + tid;
            const int row   = c >> 2;                    // 4 x 16B chunks per row
            const int slot  = c & 3;
            const int gslot = slot ^ ((row >> 1) & 3);   // T2 involution
            gload16(Ag + (size_t)row * K + t * BK + gslot * 8, la + c * 16);
            gload16(Bg + (size_t)row * K + t * BK + gslot * 8, lb + c * 16);
        }
    };
    auto frag = [&](const unsigned short* lds, int row) -> bf16x8 {
        const int slot = ls ^ ((row >> 1) & 3);
        return *(const bf16x8*)((const char*)lds + row * (BK * 2) + slot * 16);
    };

    f32x4 acc[4][4] = {};

    stage(0); stage(1); stage(2);      // 12 loads/thread in flight

    #pragma unroll
    for (int t = 0; t < NT; ++t) {
        // counted wait: slabs t+1, t+2 (8 loads) stay IN FLIGHT
        if (t <= NT - 3)      asm volatile("s_waitcnt vmcnt(8)" ::: "memory");
        else if (t == NT - 2) asm volatile("s_waitcnt vmcnt(4)" ::: "memory");
        else                  asm volatile("s_waitcnt vmcnt(0)" ::: "memory");
        __builtin_amdgcn_s_barrier();        // RAW barrier — no drain
        __builtin_amdgcn_sched_barrier(0);   // pin: no ds_read hoists above
        if (t + 3 < NT) stage(t + 3);        // slot (t-1)&3: WAR-safe

        bf16x8 af[4], bf[4];
        #pragma unroll
        for (int m = 0; m < 4; ++m) af[m] = frag(As[t & 3], wr + m * 16 + lr);
        #pragma unroll
        for (int n = 0; n < 4; ++n) bf[n] = frag(Bs[t & 3], wc + n * 16 + lr);

        __builtin_amdgcn_s_setprio(1);
        #pragma unroll
        for (int m = 0; m < 4; ++m)
            #pragma unroll
            for (int n = 0; n < 4; ++n)
                acc[m][n] = __builtin_amdgcn_mfma_f32_16x16x32_bf16(
                    af[m], bf[n], acc[m][n], 0, 0, 0);
        __builtin_amdgcn_s_setprio(0);
    }

    // epilogue: C/D layout col=lane&15, row=(lane>>4)*4+j (HW-verified)
    const int r0 = bm * BM + wr + ls * 4;
    const int c0 = bn * BN + wc + lr;
    #pragma unroll
    for (int n = 0; n < 4; ++n) {
        const int gc = c0 + n * 16;
        const float bv = bias[gc];
        #pragma unroll
        for (int m = 0; m < 4; ++m) {
            #pragma unroll
            for (int j = 0; j < 4; ++j) {
                const int gr = r0 + m * 16 + j;
                const float v = acc[m][n][j] + bv;
                if constexpr (OUT_BF16)
                    ((unsigned short*)Cvoid)[(size_t)gr * N + gc] = f2bf(v);
                else
                    ((float*)Cvoid)[(size_t)gr * N + gc] = v;
            }
        }
    }
}

// ---------------- per-token attention over heads (8x8 softmax) --------------
__global__ __launch_bounds__(256) void attn_heads(
        const unsigned short* __restrict__ qkv,   // [M][1536] bf16
        unsigned short* __restrict__ val,         // [M][512]  bf16
        int M) {
    const int t    = blockIdx.x * 4 + (threadIdx.x >> 6);
    const int lane = threadIdx.x & 63;
    const int h    = lane >> 3;
    const int c    = lane & 7;
    const unsigned short* base = qkv + (size_t)t * 1536;

    s16x8 q8 = *(const s16x8*)(base + h * 192 + c * 8);
    float qf[8];
    #pragma unroll
    for (int j = 0; j < 8; ++j) qf[j] = bf2f((unsigned short)q8[j]);

    float s[8];
    #pragma unroll
    for (int g = 0; g < 8; ++g) {
        s16x8 k8 = *(const s16x8*)(base + g * 192 + 64 + c * 8);
        float p = 0.f;
        #pragma unroll
        for (int j = 0; j < 8; ++j) p += qf[j] * bf2f((unsigned short)k8[j]);
        s[g] = p;
    }
    #pragma unroll
    for (int mask = 1; mask <= 4; mask <<= 1)
        #pragma unroll
        for (int g = 0; g < 8; ++g)
            s[g] += __shfl_xor(s[g], mask, 64);

    float mx = -1e30f;
    #pragma unroll
    for (int g = 0; g < 8; ++g) { s[g] *= 0.125f; mx = fmaxf(mx, s[g]); }
    float sum = 0.f;
    #pragma unroll
    for (int g = 0; g < 8; ++g) { s[g] = __expf(s[g] - mx); sum += s[g]; }
    const float inv = 1.f / sum;

    float acc[8] = {0.f,0.f,0.f,0.f,0.f,0.f,0.f,0.f};
    #pragma unroll
    for (int g = 0; g < 8; ++g) {
        s16x8 v8 = *(const s16x8*)(base + g * 192 + 128 + c * 8);
        const float ag = s[g] * inv;
        #pragma unroll
        for (int j = 0; j < 8; ++j) acc[j] += ag * bf2f((unsigned short)v8[j]);
    }
    s16x8 ov;
    #pragma unroll
    for (int j = 0; j < 8; ++j) ov[j] = (short)f2bf(acc[j]);
    *(s16x8*)(val + (size_t)t * 512 + h * 64 + c * 8) = ov;
}

// ---------------------------------------------------------------------------
extern "C" void kernel_launch(void* const* d_in, const int* in_sizes, int n_in,
                              void* d_out, int out_size, void* d_ws, size_t ws_size,
                              hipStream_t stream) {
    const float* x     = (const float*)d_in[0];
    const float* w_qkv = (const float*)d_in[1];
    const float* b_qkv = (const float*)d_in[2];
    const float* w_out = (const float*)d_in[3];
    const float* b_out = (const float*)d_in[4];
    float* out = (float*)d_out;

    const int DM = 512;
    const int M  = in_sizes[0] / DM;      // 61440 tokens

    unsigned short* xb    = (unsigned short*)d_ws;          // M*512
    unsigned short* wqkvb = xb + (size_t)M * DM;            // 1536*512
    unsigned short* woutb = wqkvb + (size_t)3 * DM * DM;    // 512*512
    unsigned short* qkvb  = woutb + (size_t)DM * DM;        // M*1536
    unsigned short* valb  = qkvb + (size_t)M * 3 * DM;      // M*512

    cvt_bf16<<<2048, 256, 0, stream>>>(x, xb, M * DM / 4);
    cvt_bf16<<<96,   256, 0, stream>>>(w_qkv, wqkvb, 3 * DM * DM / 4);
    cvt_bf16<<<32,   256, 0, stream>>>(w_out, woutb, DM * DM / 4);

    // GEMM1: qkv[M][1536] = x @ w_qkv^T + b_qkv (bf16 out). grid 480*12=5760
    gemm128r<512, true><<<dim3((M / 128) * (3 * DM / 128)), 256, 0, stream>>>(
        xb, wqkvb, b_qkv, qkvb, M, 3 * DM, 3 * DM / 128);

    // per-token attention over heads
    attn_heads<<<M / 4, 256, 0, stream>>>(qkvb, valb, M);

    // GEMM2: out[M][512] = val @ w_out^T + b_out (fp32 out). grid 480*4=1920
    gemm128r<512, false><<<dim3((M / 128) * (DM / 128)), 256, 0, stream>>>(
        valb, woutb, b_out, out, M, DM, DM / 128);
}